// Round 1
// baseline (254.266 us; speedup 1.0000x reference)
//
#include <hip/hip_runtime.h>
#include <math.h>

// Network_22892175688023 — MoE/MANN generator, fp32 baseline.
//
// Pipeline (B=1024):
//   enc_pre : h1raw = xs@w1^T + b1   [1024,64]   + column stats (atomics)
//   enc_mid : h2raw = relu(bn1(h1raw))@w2^T + b2 [1024,32] + stats2
//   gate    : latent=relu(bn2(h2raw)); gating MLP -> bc[1024,8];
//             bb_i = bc@eb_i; zero h1pre/h2pre/out
//   gen1    : h1pre += sum over experts  bc_e * (xs @ ew1_e)      (K-split by expert, atomics)
//   gen2    : h2pre += bc_e * (elu(h1pre+bb1) @ ew2_e)
//   gen3    : out   += bc_e * (elu(h2pre+bb2) @ ew3_e)  (+bb3 on z==0)

#define DIN 103
#define L1W 64
#define L2W 32
#define NE  8
#define GH  64
#define HH  256
#define DOUT 51
#define EPSBN 1e-5f

__device__ __forceinline__ float eluf(float v) { return v > 0.f ? v : (expf(v) - 1.f); }

// ---------------- ws layout (floats) ----------------
// h1raw : 0        (65536)
// h2raw : 65536    (32768)
// bc    : 98304    (8192)
// bb1   : 106496   (262144)
// bb2   : 368640   (262144)
// bb3   : 630784   (52224)
// h1pre : 683008   (262144)   } contiguous, zeroed together
// h2pre : 945152   (262144)   }
// stats : 1207296  (192)  s1[64] q1[64] s2[32] q2[32]

// =============== encoder layer 1 + stats ===============
__global__ __launch_bounds__(256) void enc_pre(const float* __restrict__ x,
    const float* __restrict__ w1, const float* __restrict__ b1,
    float* __restrict__ h1raw, float* __restrict__ stats) {
  __shared__ float w1L[DIN * L1W];   // 26.4 KB
  __shared__ float lsum[L1W], lsq[L1W];
  int t = threadIdx.x;
  for (int idx = t; idx < DIN * L1W; idx += 256) w1L[idx] = w1[idx];
  if (t < L1W) { lsum[t] = 0.f; lsq[t] = 0.f; }
  __syncthreads();
  int wave = t >> 6, j = t & 63;
  int row = blockIdx.x * 4 + wave;              // one wave per batch row
  const float* xr = x + row * DIN;
  float acc = b1[j];
  for (int i = 0; i < DIN; ++i) {
    float xv = xr[i];                            // broadcast across lanes
    if (i >= 100) xv *= 100.f;                   // x[:,100:103] *= 100
    acc = fmaf(xv, w1L[j * DIN + i], acc);       // 2-way bank alias = free
  }
  h1raw[row * L1W + j] = acc;
  atomicAdd(&lsum[j], acc);
  atomicAdd(&lsq[j], acc * acc);
  __syncthreads();
  if (t < L1W) { atomicAdd(&stats[t], lsum[t]); atomicAdd(&stats[64 + t], lsq[t]); }
}

// =============== bn1+relu, encoder layer 2 + stats2 ===============
__global__ __launch_bounds__(256) void enc_mid(const float* __restrict__ h1raw,
    const float* __restrict__ stats, const float* __restrict__ gamma1, const float* __restrict__ beta1,
    const float* __restrict__ w2, const float* __restrict__ b2,
    float* __restrict__ h2raw, float* __restrict__ stats2) {
  __shared__ float w2L[L1W * 33];                // transposed, padded: [k][j]
  __shared__ float sc1[L1W], sh1[L1W];
  __shared__ float ls[L2W], lq[L2W];
  int t = threadIdx.x;
  for (int idx = t; idx < L1W * L2W; idx += 256) {
    int j = idx & 31, k = idx >> 5;
    w2L[k * 33 + j] = w2[j * L1W + k];
  }
  if (t < L1W) {
    float m = stats[t] * (1.f / 1024.f);
    float v = stats[64 + t] * (1.f / 1024.f) - m * m;
    float sc = gamma1[t] * rsqrtf(v + EPSBN);
    sc1[t] = sc; sh1[t] = beta1[t] - m * sc;
  }
  if (t < L2W) { ls[t] = 0.f; lq[t] = 0.f; }
  __syncthreads();
  int wave = t >> 6, l = t & 63;
  int j = l & 31, kh = l >> 5;                    // lanes split K in half
  int row = blockIdx.x * 4 + wave;
  const float* hr = h1raw + row * L1W;
  float acc = 0.f;
  for (int kk = 0; kk < 32; ++kk) {
    int k = kh * 32 + kk;
    float xv = fmaxf(fmaf(hr[k], sc1[k], sh1[k]), 0.f);
    acc = fmaf(xv, w2L[k * 33 + j], acc);
  }
  float tot = acc + __shfl_xor(acc, 32);
  if (kh == 0) {
    tot += b2[j];
    h2raw[row * L2W + j] = tot;
    atomicAdd(&ls[j], tot);
    atomicAdd(&lq[j], tot * tot);
  }
  __syncthreads();
  if (t < L2W) { atomicAdd(&stats2[t], ls[t]); atomicAdd(&stats2[32 + t], lq[t]); }
}

// =============== bn2+relu, gating MLP, bc, bb1/2/3, zero accumulators ===============
__global__ __launch_bounds__(256) void gate_kernel(
    const float* __restrict__ h2raw, const float* __restrict__ stats2,
    const float* __restrict__ gamma2, const float* __restrict__ beta2,
    const float* __restrict__ gw1, const float* __restrict__ gb1,
    const float* __restrict__ gw2, const float* __restrict__ gb2,
    const float* __restrict__ gw3, const float* __restrict__ gb3,
    const float* __restrict__ eb1, const float* __restrict__ eb2, const float* __restrict__ eb3,
    float* __restrict__ bc, float* __restrict__ bb1, float* __restrict__ bb2, float* __restrict__ bb3,
    float* __restrict__ zeroPre /*h1pre..h2pre, 524288 f*/, float* __restrict__ zeroOut /*52224 f*/) {
  __shared__ float gw1L[GH * 33];
  __shared__ float gw2L[GH * 65];
  __shared__ float gw3L[NE * 65];
  __shared__ float eb1L[NE * HH], eb2L[NE * HH], eb3L[NE * DOUT];
  __shared__ float sc2[L2W], sh2[L2W];
  __shared__ float gb1L[GH], gb2L[GH], gb3L[NE];
  __shared__ float latb[4][L2W], g1b[4][GH], g2b[4][GH], lgb[4][NE];
  int t = threadIdx.x;
  { // zero the atomic accumulators + output
    int gid = blockIdx.x * 256 + t;
    float4* zp = (float4*)zeroPre;
    for (int i = gid; i < 131072; i += 65536) zp[i] = make_float4(0.f, 0.f, 0.f, 0.f);
    float4* zo = (float4*)zeroOut;
    if (gid < 13056) zo[gid] = make_float4(0.f, 0.f, 0.f, 0.f);
  }
  for (int idx = t; idx < GH * L2W; idx += 256) { int jj = idx >> 5, kk = idx & 31; gw1L[jj * 33 + kk] = gw1[idx]; }
  for (int idx = t; idx < GH * GH;  idx += 256) { int jj = idx >> 6, kk = idx & 63; gw2L[jj * 65 + kk] = gw2[idx]; }
  for (int idx = t; idx < NE * GH;  idx += 256) { int jj = idx >> 6, kk = idx & 63; gw3L[jj * 65 + kk] = gw3[idx]; }
  for (int idx = t; idx < NE * HH;  idx += 256) { eb1L[idx] = eb1[idx]; eb2L[idx] = eb2[idx]; }
  for (int idx = t; idx < NE * DOUT; idx += 256) eb3L[idx] = eb3[idx];
  if (t < GH) { gb1L[t] = gb1[t]; gb2L[t] = gb2[t]; }
  if (t < NE) gb3L[t] = gb3[t];
  if (t < L2W) {
    float m = stats2[t] * (1.f / 1024.f);
    float v = stats2[32 + t] * (1.f / 1024.f) - m * m;
    float sc = gamma2[t] * rsqrtf(v + EPSBN);
    sc2[t] = sc; sh2[t] = beta2[t] - m * sc;
  }
  __syncthreads();
  int wave = t >> 6, l = t & 63;
  int row = blockIdx.x * 4 + wave;                // one wave per row
  if (l < L2W) {
    float hv = h2raw[row * L2W + l];
    latb[wave][l] = fmaxf(fmaf(hv, sc2[l], sh2[l]), 0.f);
  }
  __syncthreads();
  float a1 = gb1L[l];
  for (int k = 0; k < L2W; ++k) a1 = fmaf(gw1L[l * 33 + k], latb[wave][k], a1);
  g1b[wave][l] = eluf(a1);
  __syncthreads();
  float a2 = gb2L[l];
  for (int k = 0; k < GH; ++k) a2 = fmaf(gw2L[l * 65 + k], g1b[wave][k], a2);
  g2b[wave][l] = eluf(a2);
  __syncthreads();
  if (l < NE) {
    float a3 = gb3L[l];
    for (int k = 0; k < GH; ++k) a3 = fmaf(gw3L[l * 65 + k], g2b[wave][k], a3);
    lgb[wave][l] = a3;
  }
  __syncthreads();
  float bcv[NE];
  {
    float mx = -1e30f;
    for (int e = 0; e < NE; ++e) mx = fmaxf(mx, lgb[wave][e]);
    float sum = 0.f;
    for (int e = 0; e < NE; ++e) { float p = expf(lgb[wave][e] - mx); bcv[e] = p; sum += p; }
    float inv = 1.f / sum;
    for (int e = 0; e < NE; ++e) bcv[e] *= inv;
  }
  if (l < NE) bc[row * NE + l] = bcv[l];
  for (int q = 0; q < 4; ++q) {
    int c = l + q * 64;
    float s1v = 0.f, s2v = 0.f;
    for (int e = 0; e < NE; ++e) {
      s1v = fmaf(bcv[e], eb1L[e * HH + c], s1v);
      s2v = fmaf(bcv[e], eb2L[e * HH + c], s2v);
    }
    bb1[row * HH + c] = s1v;
    bb2[row * HH + c] = s2v;
  }
  if (l < DOUT) {
    float s3 = 0.f;
    for (int e = 0; e < NE; ++e) s3 = fmaf(bcv[e], eb3L[e * DOUT + l], s3);
    bb3[row * DOUT + l] = s3;
  }
}

// =============== generator GEMMs: 64x64 tile, 4x4 micro, K-split by expert ===============
// grid (mt, nt, z): block computes 64x64 C-tile over K-chunk of expert z, atomicAdds partials.

#define GBK 16

// gen1: A[b, z*128+i] = bc[b,z]*xs[b,i] (i<103, padded K=1024), B = ew1 [E*103,256]
__global__ __launch_bounds__(256, 2) void gen1(const float* __restrict__ x,
    const float* __restrict__ bc, const float* __restrict__ ew1, float* __restrict__ h1pre) {
  __shared__ __attribute__((aligned(16))) float As[GBK][68];
  __shared__ __attribute__((aligned(16))) float Bs[GBK][68];
  int t = threadIdx.x;
  int mt = blockIdx.x, nt = blockIdx.y, z = blockIdx.z;
  int tx = t & 15, ty = t >> 4;
  int ab = t >> 2, ag = (t & 3) * 4;
  int brow = mt * 64 + ab;
  float bcv = bc[brow * NE + z];
  const float* xr = x + brow * DIN;
  int bsr = t >> 4, bsn = (t & 15) * 4;
  float acc[4][4] = {};
  for (int kt = 0; kt < 8; ++kt) {          // K-chunk = 128 (one expert, padded)
    int i0 = kt * 16;
    float av[4];
#pragma unroll
    for (int jj = 0; jj < 4; ++jj) {
      int i = i0 + ag + jj;
      float xv = (i < DIN) ? xr[i] : 0.f;
      if (i >= 100) xv *= 100.f;            // i>=103 already zeroed
      av[jj] = bcv * xv;
    }
#pragma unroll
    for (int jj = 0; jj < 4; ++jj) As[ag + jj][ab] = av[jj];
    {
      int r = i0 + bsr;
      float4 w = make_float4(0.f, 0.f, 0.f, 0.f);
      if (r < DIN) w = *(const float4*)(ew1 + ((size_t)(z * DIN + r)) * HH + nt * 64 + bsn);
      *(float4*)&Bs[bsr][bsn] = w;
    }
    __syncthreads();
#pragma unroll
    for (int k = 0; k < GBK; ++k) {
      float4 a4 = *(const float4*)&As[k][ty * 4];
      float4 b4 = *(const float4*)&Bs[k][tx * 4];
      float aa[4] = {a4.x, a4.y, a4.z, a4.w};
      float bb[4] = {b4.x, b4.y, b4.z, b4.w};
#pragma unroll
      for (int im = 0; im < 4; ++im)
#pragma unroll
        for (int in = 0; in < 4; ++in) acc[im][in] = fmaf(aa[im], bb[in], acc[im][in]);
    }
    __syncthreads();
  }
#pragma unroll
  for (int im = 0; im < 4; ++im) {
    int gm = mt * 64 + ty * 4 + im;
#pragma unroll
    for (int in = 0; in < 4; ++in) {
      int gn = nt * 64 + tx * 4 + in;
      atomicAdd(&h1pre[gm * HH + gn], acc[im][in]);
    }
  }
}

// gen2: A[b, z*256+h] = bc[b,z]*elu(h1pre[b,h]+bb1[b,h]), B = ew2 [2048,256]
__global__ __launch_bounds__(256, 2) void gen2(const float* __restrict__ h1pre,
    const float* __restrict__ bb1, const float* __restrict__ bc,
    const float* __restrict__ ew2, float* __restrict__ h2pre) {
  __shared__ __attribute__((aligned(16))) float As[GBK][68];
  __shared__ __attribute__((aligned(16))) float Bs[GBK][68];
  int t = threadIdx.x;
  int mt = blockIdx.x, nt = blockIdx.y, z = blockIdx.z;
  int tx = t & 15, ty = t >> 4;
  int ab = t >> 2, ag = (t & 3) * 4;
  int brow = mt * 64 + ab;
  float bcv = bc[brow * NE + z];
  const float* hrow = h1pre + brow * HH;
  const float* brow1 = bb1 + brow * HH;
  int bsr = t >> 4, bsn = (t & 15) * 4;
  float acc[4][4] = {};
  for (int kt = 0; kt < 16; ++kt) {         // K-chunk = 256 (one expert)
    int h0 = kt * 16;
    float4 hv = *(const float4*)(hrow + h0 + ag);
    float4 bv = *(const float4*)(brow1 + h0 + ag);
    As[ag + 0][ab] = bcv * eluf(hv.x + bv.x);
    As[ag + 1][ab] = bcv * eluf(hv.y + bv.y);
    As[ag + 2][ab] = bcv * eluf(hv.z + bv.z);
    As[ag + 3][ab] = bcv * eluf(hv.w + bv.w);
    {
      float4 w = *(const float4*)(ew2 + ((size_t)(z * HH + h0 + bsr)) * HH + nt * 64 + bsn);
      *(float4*)&Bs[bsr][bsn] = w;
    }
    __syncthreads();
#pragma unroll
    for (int k = 0; k < GBK; ++k) {
      float4 a4 = *(const float4*)&As[k][ty * 4];
      float4 b4 = *(const float4*)&Bs[k][tx * 4];
      float aa[4] = {a4.x, a4.y, a4.z, a4.w};
      float bb[4] = {b4.x, b4.y, b4.z, b4.w};
#pragma unroll
      for (int im = 0; im < 4; ++im)
#pragma unroll
        for (int in = 0; in < 4; ++in) acc[im][in] = fmaf(aa[im], bb[in], acc[im][in]);
    }
    __syncthreads();
  }
#pragma unroll
  for (int im = 0; im < 4; ++im) {
    int gm = mt * 64 + ty * 4 + im;
#pragma unroll
    for (int in = 0; in < 4; ++in) {
      int gn = nt * 64 + tx * 4 + in;
      atomicAdd(&h2pre[gm * HH + gn], acc[im][in]);
    }
  }
}

// gen3: A from elu(h2pre+bb2), B = ew3 [2048,51]; out += partials (+bb3 on z==0)
__global__ __launch_bounds__(256, 2) void gen3(const float* __restrict__ h2pre,
    const float* __restrict__ bb2, const float* __restrict__ bc,
    const float* __restrict__ ew3, const float* __restrict__ bb3, float* __restrict__ out) {
  __shared__ __attribute__((aligned(16))) float As[GBK][68];
  __shared__ __attribute__((aligned(16))) float Bs[GBK][68];
  int t = threadIdx.x;
  int mt = blockIdx.x, z = blockIdx.z;
  int tx = t & 15, ty = t >> 4;
  int ab = t >> 2, ag = (t & 3) * 4;
  int brow = mt * 64 + ab;
  float bcv = bc[brow * NE + z];
  const float* hrow = h2pre + brow * HH;
  const float* brow2 = bb2 + brow * HH;
  int bsr = t >> 4, bsn = (t & 15) * 4;
  float acc[4][4] = {};
  for (int kt = 0; kt < 16; ++kt) {
    int h0 = kt * 16;
    float4 hv = *(const float4*)(hrow + h0 + ag);
    float4 bv = *(const float4*)(brow2 + h0 + ag);
    As[ag + 0][ab] = bcv * eluf(hv.x + bv.x);
    As[ag + 1][ab] = bcv * eluf(hv.y + bv.y);
    As[ag + 2][ab] = bcv * eluf(hv.z + bv.z);
    As[ag + 3][ab] = bcv * eluf(hv.w + bv.w);
    {
      const float* wp = ew3 + ((size_t)(z * HH + h0 + bsr)) * DOUT;
#pragma unroll
      for (int jj = 0; jj < 4; ++jj) {
        int n = bsn + jj;
        Bs[bsr][bsn + jj] = (n < DOUT) ? wp[n] : 0.f;
      }
    }
    __syncthreads();
#pragma unroll
    for (int k = 0; k < GBK; ++k) {
      float4 a4 = *(const float4*)&As[k][ty * 4];
      float4 b4 = *(const float4*)&Bs[k][tx * 4];
      float aa[4] = {a4.x, a4.y, a4.z, a4.w};
      float bb[4] = {b4.x, b4.y, b4.z, b4.w};
#pragma unroll
      for (int im = 0; im < 4; ++im)
#pragma unroll
        for (int in = 0; in < 4; ++in) acc[im][in] = fmaf(aa[im], bb[in], acc[im][in]);
    }
    __syncthreads();
  }
#pragma unroll
  for (int im = 0; im < 4; ++im) {
    int gm = mt * 64 + ty * 4 + im;
#pragma unroll
    for (int in = 0; in < 4; ++in) {
      int gn = tx * 4 + in;
      if (gn < DOUT) {
        float v = acc[im][in];
        if (z == 0) v += bb3[gm * DOUT + gn];
        atomicAdd(&out[gm * DOUT + gn], v);
      }
    }
  }
}

extern "C" void kernel_launch(void* const* d_in, const int* in_sizes, int n_in,
                              void* d_out, int out_size, void* d_ws, size_t ws_size,
                              hipStream_t stream) {
  const float* x      = (const float*)d_in[0];
  const float* w1     = (const float*)d_in[1];
  const float* b1     = (const float*)d_in[2];
  const float* gamma1 = (const float*)d_in[3];
  const float* beta1  = (const float*)d_in[4];
  const float* w2     = (const float*)d_in[5];
  const float* b2     = (const float*)d_in[6];
  const float* gamma2 = (const float*)d_in[7];
  const float* beta2  = (const float*)d_in[8];
  const float* gw1    = (const float*)d_in[9];
  const float* gb1    = (const float*)d_in[10];
  const float* gw2    = (const float*)d_in[11];
  const float* gb2    = (const float*)d_in[12];
  const float* gw3    = (const float*)d_in[13];
  const float* gb3    = (const float*)d_in[14];
  const float* ew1    = (const float*)d_in[15];
  const float* eb1    = (const float*)d_in[16];
  const float* ew2    = (const float*)d_in[17];
  const float* eb2    = (const float*)d_in[18];
  const float* ew3    = (const float*)d_in[19];
  const float* eb3    = (const float*)d_in[20];

  float* ws    = (float*)d_ws;
  float* h1raw = ws;
  float* h2raw = ws + 65536;
  float* bcp   = ws + 98304;
  float* bb1p  = ws + 106496;
  float* bb2p  = ws + 368640;
  float* bb3p  = ws + 630784;
  float* h1pre = ws + 683008;
  float* h2pre = ws + 945152;
  float* stats = ws + 1207296;
  float* outp  = (float*)d_out;

  hipMemsetAsync(stats, 0, 192 * sizeof(float), stream);
  enc_pre<<<256, 256, 0, stream>>>(x, w1, b1, h1raw, stats);
  enc_mid<<<256, 256, 0, stream>>>(h1raw, stats, gamma1, beta1, w2, b2, h2raw, stats + 128);
  gate_kernel<<<256, 256, 0, stream>>>(h2raw, stats + 128, gamma2, beta2,
                                       gw1, gb1, gw2, gb2, gw3, gb3,
                                       eb1, eb2, eb3,
                                       bcp, bb1p, bb2p, bb3p, h1pre, outp);
  gen1<<<dim3(16, 4, 8), 256, 0, stream>>>(x, bcp, ew1, h1pre);
  gen2<<<dim3(16, 4, 8), 256, 0, stream>>>(h1pre, bb1p, bcp, ew2, h2pre);
  gen3<<<dim3(16, 1, 8), 256, 0, stream>>>(h2pre, bb2p, bcp, ew3, bb3p, outp);
}

// Round 2
// 175.871 us; speedup vs baseline: 1.4458x; 1.4458x over previous
//
#include <hip/hip_runtime.h>
#include <math.h>

// Network_22892175688023 — round 2: MFMA bf16x3 generator, no atomics.
//
//   enc_pre : h1raw = xs@w1^T + b1 + column stats (atomics, tiny)
//   enc_mid : h2raw = relu(bn1(h1raw))@w2^T + b2 + stats2
//   gate    : latent=relu(bn2); gating MLP -> bc[1024,8]
//   gen1    : p[e] = xs @ ew1_e            (MFMA bf16x3, per-expert blocks)
//   combine : a = elu(sum_e bc_e*(p[e]+eb1_e))  -> bf16 hi/lo planes
//   gen2    : p[e] = a @ ew2_e
//   combine : a = elu(sum_e bc_e*(p[e]+eb2_e))
//   gen3    : p3[e] = a @ ew3_e  (N=51 padded to 64)
//   combine3: out = sum_e bc_e*(p3[e]+eb3_e)

#define DIN 103
#define L1W 64
#define L2W 32
#define NE  8
#define GH  64
#define HH  256
#define DOUT 51
#define EPSBN 1e-5f

typedef __attribute__((ext_vector_type(8))) short bf16x8;
typedef __attribute__((ext_vector_type(4))) float f32x4;
typedef __attribute__((ext_vector_type(8))) unsigned short us8;
typedef __attribute__((ext_vector_type(4))) unsigned short us4;

__device__ __forceinline__ float eluf(float v) { return v > 0.f ? v : (expf(v) - 1.f); }

__device__ __forceinline__ unsigned short bf16h(float f) {
  unsigned u = __float_as_uint(f);
  u += 0x7FFFu + ((u >> 16) & 1u);
  return (unsigned short)(u >> 16);
}
__device__ __forceinline__ float bf16f(unsigned short h) {
  return __uint_as_float(((unsigned)h) << 16);
}
__device__ __forceinline__ void split_bf16(float v, unsigned short& h, unsigned short& l) {
  h = bf16h(v);
  l = bf16h(v - bf16f(h));
}

// ---------------- ws layout (float offsets) ----------------
// h1raw : 0        (65536)
// h2raw : 65536    (32768)
// bc    : 98304    (8192)
// stats : 106496   (192)   s1[64] q1[64] | s2[32] q2[32]
// a_hi  : 106752   (131072 f = 262144 bf16)   [1024,256] hi plane
// a_lo  : 237824   (131072 f)
// p     : 368896   (2097152 f)  [8][1024][256] partials; reused as p3 [8][1024][64]

// =============== encoder layer 1 + stats ===============
__global__ __launch_bounds__(256) void enc_pre(const float* __restrict__ x,
    const float* __restrict__ w1, const float* __restrict__ b1,
    float* __restrict__ h1raw, float* __restrict__ stats) {
  __shared__ float w1L[DIN * L1W];
  __shared__ float lsum[L1W], lsq[L1W];
  int t = threadIdx.x;
  for (int idx = t; idx < DIN * L1W; idx += 256) w1L[idx] = w1[idx];
  if (t < L1W) { lsum[t] = 0.f; lsq[t] = 0.f; }
  __syncthreads();
  int wave = t >> 6, j = t & 63;
  int row = blockIdx.x * 4 + wave;
  const float* xr = x + row * DIN;
  float acc = b1[j];
  for (int i = 0; i < DIN; ++i) {
    float xv = xr[i];
    if (i >= 100) xv *= 100.f;
    acc = fmaf(xv, w1L[j * DIN + i], acc);
  }
  h1raw[row * L1W + j] = acc;
  atomicAdd(&lsum[j], acc);
  atomicAdd(&lsq[j], acc * acc);
  __syncthreads();
  if (t < L1W) { atomicAdd(&stats[t], lsum[t]); atomicAdd(&stats[64 + t], lsq[t]); }
}

// =============== bn1+relu, encoder layer 2 + stats2 ===============
__global__ __launch_bounds__(256) void enc_mid(const float* __restrict__ h1raw,
    const float* __restrict__ stats, const float* __restrict__ gamma1, const float* __restrict__ beta1,
    const float* __restrict__ w2, const float* __restrict__ b2,
    float* __restrict__ h2raw, float* __restrict__ stats2) {
  __shared__ float w2L[L1W * 33];
  __shared__ float sc1[L1W], sh1[L1W];
  __shared__ float ls[L2W], lq[L2W];
  int t = threadIdx.x;
  for (int idx = t; idx < L1W * L2W; idx += 256) {
    int j = idx & 31, k = idx >> 5;
    w2L[k * 33 + j] = w2[j * L1W + k];
  }
  if (t < L1W) {
    float m = stats[t] * (1.f / 1024.f);
    float v = stats[64 + t] * (1.f / 1024.f) - m * m;
    float sc = gamma1[t] * rsqrtf(v + EPSBN);
    sc1[t] = sc; sh1[t] = beta1[t] - m * sc;
  }
  if (t < L2W) { ls[t] = 0.f; lq[t] = 0.f; }
  __syncthreads();
  int wave = t >> 6, l = t & 63;
  int j = l & 31, kh = l >> 5;
  int row = blockIdx.x * 4 + wave;
  const float* hr = h1raw + row * L1W;
  float acc = 0.f;
  for (int kk = 0; kk < 32; ++kk) {
    int k = kh * 32 + kk;
    float xv = fmaxf(fmaf(hr[k], sc1[k], sh1[k]), 0.f);
    acc = fmaf(xv, w2L[k * 33 + j], acc);
  }
  float tot = acc + __shfl_xor(acc, 32);
  if (kh == 0) {
    tot += b2[j];
    h2raw[row * L2W + j] = tot;
    atomicAdd(&ls[j], tot);
    atomicAdd(&lq[j], tot * tot);
  }
  __syncthreads();
  if (t < L2W) { atomicAdd(&stats2[t], ls[t]); atomicAdd(&stats2[32 + t], lq[t]); }
}

// =============== bn2+relu, gating MLP -> bc ===============
__global__ __launch_bounds__(256) void gate_kernel(
    const float* __restrict__ h2raw, const float* __restrict__ stats2,
    const float* __restrict__ gamma2, const float* __restrict__ beta2,
    const float* __restrict__ gw1, const float* __restrict__ gb1,
    const float* __restrict__ gw2, const float* __restrict__ gb2,
    const float* __restrict__ gw3, const float* __restrict__ gb3,
    float* __restrict__ bc) {
  __shared__ float gw1L[GH * 33];
  __shared__ float gw2L[GH * 65];
  __shared__ float gw3L[NE * 65];
  __shared__ float sc2[L2W], sh2[L2W];
  __shared__ float gb1L[GH], gb2L[GH], gb3L[NE];
  __shared__ float latb[4][L2W], g1b[4][GH], g2b[4][GH], lgb[4][NE];
  int t = threadIdx.x;
  for (int idx = t; idx < GH * L2W; idx += 256) { int jj = idx >> 5, kk = idx & 31; gw1L[jj * 33 + kk] = gw1[idx]; }
  for (int idx = t; idx < GH * GH;  idx += 256) { int jj = idx >> 6, kk = idx & 63; gw2L[jj * 65 + kk] = gw2[idx]; }
  for (int idx = t; idx < NE * GH;  idx += 256) { int jj = idx >> 6, kk = idx & 63; gw3L[jj * 65 + kk] = gw3[idx]; }
  if (t < GH) { gb1L[t] = gb1[t]; gb2L[t] = gb2[t]; }
  if (t < NE) gb3L[t] = gb3[t];
  if (t < L2W) {
    float m = stats2[t] * (1.f / 1024.f);
    float v = stats2[32 + t] * (1.f / 1024.f) - m * m;
    float sc = gamma2[t] * rsqrtf(v + EPSBN);
    sc2[t] = sc; sh2[t] = beta2[t] - m * sc;
  }
  __syncthreads();
  int wave = t >> 6, l = t & 63;
  int row = blockIdx.x * 4 + wave;
  if (l < L2W) {
    float hv = h2raw[row * L2W + l];
    latb[wave][l] = fmaxf(fmaf(hv, sc2[l], sh2[l]), 0.f);
  }
  __syncthreads();
  float a1 = gb1L[l];
  for (int k = 0; k < L2W; ++k) a1 = fmaf(gw1L[l * 33 + k], latb[wave][k], a1);
  g1b[wave][l] = eluf(a1);
  __syncthreads();
  float a2 = gb2L[l];
  for (int k = 0; k < GH; ++k) a2 = fmaf(gw2L[l * 65 + k], g1b[wave][k], a2);
  g2b[wave][l] = eluf(a2);
  __syncthreads();
  if (l < NE) {
    float a3 = gb3L[l];
    for (int k = 0; k < GH; ++k) a3 = fmaf(gw3L[l * 65 + k], g2b[wave][k], a3);
    lgb[wave][l] = a3;
  }
  __syncthreads();
  if (l < NE) {
    float mx = -1e30f;
    for (int e = 0; e < NE; ++e) mx = fmaxf(mx, lgb[wave][e]);
    float sum = 0.f, mine = 0.f;
    for (int e = 0; e < NE; ++e) {
      float p = expf(lgb[wave][e] - mx);
      if (e == l) mine = p;
      sum += p;
    }
    bc[row * NE + l] = mine / sum;
  }
}

// =============== MFMA generator kernels ===============
// LDS chunk layout (fragment order): element (r,k) of a 32-k chunk lives at
// short index (r>>4)*512 + (k>>3)*128 + (r&15)*8 + (k&7); lane l of subtile s
// reads its whole 8-bf16 fragment at s*512 + l*8  (perfectly coalesced b128).

// gen1: p[e] = xs @ ew1_e.  grid (8,2,8), block 256 (4 waves), tile 128x128, K=103->128.
__global__ __launch_bounds__(256) void gen1(const float* __restrict__ x,
    const float* __restrict__ ew1, float* __restrict__ p) {
  __shared__ __attribute__((aligned(16))) unsigned short Ah[4096], Al[4096], Bh[4096], Bl[4096];
  int t = threadIdx.x;
  int M0 = blockIdx.x * 128, N0 = blockIdx.y * 128, e = blockIdx.z;
  int w = t >> 6, l = t & 63;
  int wm = w & 1, wn = w >> 1;
  f32x4 acc[4][4] = {};
  int ar = t >> 1, akh = (t & 1) * 16;
  int bn = t & 127, bkh = (t >> 7) * 16;
  const float* xrow = x + (size_t)(M0 + ar) * DIN;
  for (int kc = 0; kc < 4; ++kc) {
    int k0 = kc * 32;
    { // stage A (x, scaled cols, zero-pad K)
      us8 h0 = {0}, h1 = {0}, l0 = {0}, l1 = {0};
#pragma unroll
      for (int j = 0; j < 8; ++j) {
        int i = k0 + akh + j;
        float v = 0.f;
        if (i < DIN) { v = xrow[i]; if (i >= 100) v *= 100.f; }
        unsigned short H, L; split_bf16(v, H, L); h0[j] = H; l0[j] = L;
        i += 8; v = 0.f;
        if (i < DIN) { v = xrow[i]; if (i >= 100) v *= 100.f; }
        split_bf16(v, H, L); h1[j] = H; l1[j] = L;
      }
      int base = ((ar >> 4) << 9) + ((akh >> 3) << 7) + ((ar & 15) << 3);
      *(us8*)(Ah + base) = h0; *(us8*)(Ah + base + 128) = h1;
      *(us8*)(Al + base) = l0; *(us8*)(Al + base + 128) = l1;
    }
    { // stage B (ew1_e transposed, zero-pad K)
      us8 h0 = {0}, h1 = {0}, l0 = {0}, l1 = {0};
#pragma unroll
      for (int j = 0; j < 8; ++j) {
        int i = k0 + bkh + j;
        float v = (i < DIN) ? ew1[((size_t)e * DIN + i) * HH + N0 + bn] : 0.f;
        unsigned short H, L; split_bf16(v, H, L); h0[j] = H; l0[j] = L;
        i += 8;
        v = (i < DIN) ? ew1[((size_t)e * DIN + i) * HH + N0 + bn] : 0.f;
        split_bf16(v, H, L); h1[j] = H; l1[j] = L;
      }
      int base = ((bn >> 4) << 9) + ((bkh >> 3) << 7) + ((bn & 15) << 3);
      *(us8*)(Bh + base) = h0; *(us8*)(Bh + base + 128) = h1;
      *(us8*)(Bl + base) = l0; *(us8*)(Bl + base + 128) = l1;
    }
    __syncthreads();
    bf16x8 aH[4], aL[4], bH[4], bL[4];
#pragma unroll
    for (int im = 0; im < 4; ++im) {
      int off = (wm * 4 + im) * 512 + l * 8;
      aH[im] = *(const bf16x8*)(Ah + off);
      aL[im] = *(const bf16x8*)(Al + off);
    }
#pragma unroll
    for (int in = 0; in < 4; ++in) {
      int off = (wn * 4 + in) * 512 + l * 8;
      bH[in] = *(const bf16x8*)(Bh + off);
      bL[in] = *(const bf16x8*)(Bl + off);
    }
#pragma unroll
    for (int im = 0; im < 4; ++im)
#pragma unroll
      for (int in = 0; in < 4; ++in) {
        acc[im][in] = __builtin_amdgcn_mfma_f32_16x16x32_bf16(aH[im], bH[in], acc[im][in], 0, 0, 0);
        acc[im][in] = __builtin_amdgcn_mfma_f32_16x16x32_bf16(aL[im], bH[in], acc[im][in], 0, 0, 0);
        acc[im][in] = __builtin_amdgcn_mfma_f32_16x16x32_bf16(aH[im], bL[in], acc[im][in], 0, 0, 0);
      }
    __syncthreads();
  }
  int q = l >> 4, c = l & 15;
  float* pe = p + ((size_t)e << 18);
#pragma unroll
  for (int im = 0; im < 4; ++im) {
    int m0 = M0 + wm * 64 + im * 16 + q * 4;
#pragma unroll
    for (int in = 0; in < 4; ++in) {
      int col = N0 + wn * 64 + in * 16 + c;
#pragma unroll
      for (int r = 0; r < 4; ++r) pe[(size_t)(m0 + r) * HH + col] = acc[im][in][r];
    }
  }
}

// gen2: p[e] = a @ ew2_e.  A planes already bf16 hi/lo.  grid (8,2,8), K=256.
__global__ __launch_bounds__(256) void gen2(const unsigned short* __restrict__ aHg,
    const unsigned short* __restrict__ aLg, const float* __restrict__ ew2, float* __restrict__ p) {
  __shared__ __attribute__((aligned(16))) unsigned short Ah[4096], Al[4096], Bh[4096], Bl[4096];
  int t = threadIdx.x;
  int M0 = blockIdx.x * 128, N0 = blockIdx.y * 128, e = blockIdx.z;
  int w = t >> 6, l = t & 63;
  int wm = w & 1, wn = w >> 1;
  f32x4 acc[4][4] = {};
  int ar = t >> 1, akh = (t & 1) * 16;
  int bn = t & 127, bkh = (t >> 7) * 16;
  for (int kc = 0; kc < 8; ++kc) {
    int k0 = kc * 32;
    { // stage A: straight bf16 copy
      const us8* sh = (const us8*)(aHg + (size_t)(M0 + ar) * HH + k0 + akh);
      const us8* sl = (const us8*)(aLg + (size_t)(M0 + ar) * HH + k0 + akh);
      int base = ((ar >> 4) << 9) + ((akh >> 3) << 7) + ((ar & 15) << 3);
      *(us8*)(Ah + base) = sh[0]; *(us8*)(Ah + base + 128) = sh[1];
      *(us8*)(Al + base) = sl[0]; *(us8*)(Al + base + 128) = sl[1];
    }
    { // stage B (ew2_e transposed)
      us8 h0, h1, l0, l1;
#pragma unroll
      for (int j = 0; j < 8; ++j) {
        float v = ew2[((size_t)e * HH + k0 + bkh + j) * HH + N0 + bn];
        unsigned short H, L; split_bf16(v, H, L); h0[j] = H; l0[j] = L;
        v = ew2[((size_t)e * HH + k0 + bkh + 8 + j) * HH + N0 + bn];
        split_bf16(v, H, L); h1[j] = H; l1[j] = L;
      }
      int base = ((bn >> 4) << 9) + ((bkh >> 3) << 7) + ((bn & 15) << 3);
      *(us8*)(Bh + base) = h0; *(us8*)(Bh + base + 128) = h1;
      *(us8*)(Bl + base) = l0; *(us8*)(Bl + base + 128) = l1;
    }
    __syncthreads();
    bf16x8 aH[4], aL[4], bH[4], bL[4];
#pragma unroll
    for (int im = 0; im < 4; ++im) {
      int off = (wm * 4 + im) * 512 + l * 8;
      aH[im] = *(const bf16x8*)(Ah + off);
      aL[im] = *(const bf16x8*)(Al + off);
    }
#pragma unroll
    for (int in = 0; in < 4; ++in) {
      int off = (wn * 4 + in) * 512 + l * 8;
      bH[in] = *(const bf16x8*)(Bh + off);
      bL[in] = *(const bf16x8*)(Bl + off);
    }
#pragma unroll
    for (int im = 0; im < 4; ++im)
#pragma unroll
      for (int in = 0; in < 4; ++in) {
        acc[im][in] = __builtin_amdgcn_mfma_f32_16x16x32_bf16(aH[im], bH[in], acc[im][in], 0, 0, 0);
        acc[im][in] = __builtin_amdgcn_mfma_f32_16x16x32_bf16(aL[im], bH[in], acc[im][in], 0, 0, 0);
        acc[im][in] = __builtin_amdgcn_mfma_f32_16x16x32_bf16(aH[im], bL[in], acc[im][in], 0, 0, 0);
      }
    __syncthreads();
  }
  int q = l >> 4, c = l & 15;
  float* pe = p + ((size_t)e << 18);
#pragma unroll
  for (int im = 0; im < 4; ++im) {
    int m0 = M0 + wm * 64 + im * 16 + q * 4;
#pragma unroll
    for (int in = 0; in < 4; ++in) {
      int col = N0 + wn * 64 + in * 16 + c;
#pragma unroll
      for (int r = 0; r < 4; ++r) pe[(size_t)(m0 + r) * HH + col] = acc[im][in][r];
    }
  }
}

// gen3: p3[e] = a @ ew3_e  (N=51 pad 64).  grid (8,1,8), tile 128x64, K=256.
__global__ __launch_bounds__(256) void gen3(const unsigned short* __restrict__ aHg,
    const unsigned short* __restrict__ aLg, const float* __restrict__ ew3, float* __restrict__ p3) {
  __shared__ __attribute__((aligned(16))) unsigned short Ah[4096], Al[4096], Bh[2048], Bl[2048];
  int t = threadIdx.x;
  int M0 = blockIdx.x * 128, e = blockIdx.z;
  int w = t >> 6, l = t & 63;
  int wm = w & 1, wn = w >> 1;
  f32x4 acc[4][2] = {};
  int ar = t >> 1, akh = (t & 1) * 16;
  int bn = t & 63, bkh = (t >> 6) * 8;
  for (int kc = 0; kc < 8; ++kc) {
    int k0 = kc * 32;
    {
      const us8* sh = (const us8*)(aHg + (size_t)(M0 + ar) * HH + k0 + akh);
      const us8* sl = (const us8*)(aLg + (size_t)(M0 + ar) * HH + k0 + akh);
      int base = ((ar >> 4) << 9) + ((akh >> 3) << 7) + ((ar & 15) << 3);
      *(us8*)(Ah + base) = sh[0]; *(us8*)(Ah + base + 128) = sh[1];
      *(us8*)(Al + base) = sl[0]; *(us8*)(Al + base + 128) = sl[1];
    }
    {
      us8 h0 = {0}, l0 = {0};
      if (bn < DOUT) {
#pragma unroll
        for (int j = 0; j < 8; ++j) {
          float v = ew3[((size_t)e * HH + k0 + bkh + j) * DOUT + bn];
          unsigned short H, L; split_bf16(v, H, L); h0[j] = H; l0[j] = L;
        }
      }
      int base = ((bn >> 4) << 9) + ((bkh >> 3) << 7) + ((bn & 15) << 3);
      *(us8*)(Bh + base) = h0;
      *(us8*)(Bl + base) = l0;
    }
    __syncthreads();
    bf16x8 aH[4], aL[4], bH[2], bL[2];
#pragma unroll
    for (int im = 0; im < 4; ++im) {
      int off = (wm * 4 + im) * 512 + l * 8;
      aH[im] = *(const bf16x8*)(Ah + off);
      aL[im] = *(const bf16x8*)(Al + off);
    }
#pragma unroll
    for (int in = 0; in < 2; ++in) {
      int off = (wn * 2 + in) * 512 + l * 8;
      bH[in] = *(const bf16x8*)(Bh + off);
      bL[in] = *(const bf16x8*)(Bl + off);
    }
#pragma unroll
    for (int im = 0; im < 4; ++im)
#pragma unroll
      for (int in = 0; in < 2; ++in) {
        acc[im][in] = __builtin_amdgcn_mfma_f32_16x16x32_bf16(aH[im], bH[in], acc[im][in], 0, 0, 0);
        acc[im][in] = __builtin_amdgcn_mfma_f32_16x16x32_bf16(aL[im], bH[in], acc[im][in], 0, 0, 0);
        acc[im][in] = __builtin_amdgcn_mfma_f32_16x16x32_bf16(aH[im], bL[in], acc[im][in], 0, 0, 0);
      }
    __syncthreads();
  }
  int q = l >> 4, c = l & 15;
  float* pe = p3 + ((size_t)e << 16);
#pragma unroll
  for (int im = 0; im < 4; ++im) {
    int m0 = M0 + wm * 64 + im * 16 + q * 4;
#pragma unroll
    for (int in = 0; in < 2; ++in) {
      int col = wn * 32 + in * 16 + c;
#pragma unroll
      for (int r = 0; r < 4; ++r) pe[(size_t)(m0 + r) * 64 + col] = acc[im][in][r];
    }
  }
}

// combine: a = elu(sum_e bc_e*(p[e]+eb_e)) -> bf16 hi/lo planes. 256 blocks x 256.
__global__ __launch_bounds__(256) void combine12(const float* __restrict__ p,
    const float* __restrict__ bc, const float* __restrict__ eb,
    unsigned short* __restrict__ ah, unsigned short* __restrict__ al) {
  int gid = blockIdx.x * 256 + threadIdx.x;   // 65536 = 1024 * 64
  int b = gid >> 6, hq = (gid & 63) * 4;
  float wv[NE];
#pragma unroll
  for (int e = 0; e < NE; ++e) wv[e] = bc[b * NE + e];
  float4 s = make_float4(0.f, 0.f, 0.f, 0.f);
#pragma unroll
  for (int e = 0; e < NE; ++e) {
    float4 pv = *(const float4*)(p + ((size_t)e << 18) + (size_t)b * HH + hq);
    float4 ev = *(const float4*)(eb + e * HH + hq);
    s.x = fmaf(wv[e], pv.x + ev.x, s.x);
    s.y = fmaf(wv[e], pv.y + ev.y, s.y);
    s.z = fmaf(wv[e], pv.z + ev.z, s.z);
    s.w = fmaf(wv[e], pv.w + ev.w, s.w);
  }
  float v0 = eluf(s.x), v1 = eluf(s.y), v2 = eluf(s.z), v3 = eluf(s.w);
  us4 H, L;
  unsigned short hh, ll;
  split_bf16(v0, hh, ll); H[0] = hh; L[0] = ll;
  split_bf16(v1, hh, ll); H[1] = hh; L[1] = ll;
  split_bf16(v2, hh, ll); H[2] = hh; L[2] = ll;
  split_bf16(v3, hh, ll); H[3] = hh; L[3] = ll;
  *(us4*)(ah + (size_t)b * HH + hq) = H;
  *(us4*)(al + (size_t)b * HH + hq) = L;
}

// combine3: out = sum_e bc_e*(p3[e]+eb3_e), cols<51.
__global__ __launch_bounds__(256) void combine3(const float* __restrict__ p3,
    const float* __restrict__ bc, const float* __restrict__ eb3, float* __restrict__ out) {
  int gid = blockIdx.x * 256 + threadIdx.x;   // 65536 = 1024 * 64
  int b = gid >> 6, o = gid & 63;
  if (o >= DOUT) return;
  float s = 0.f;
#pragma unroll
  for (int e = 0; e < NE; ++e)
    s = fmaf(bc[b * NE + e], p3[((size_t)e << 16) + (size_t)b * 64 + o] + eb3[e * DOUT + o], s);
  out[(size_t)b * DOUT + o] = s;
}

extern "C" void kernel_launch(void* const* d_in, const int* in_sizes, int n_in,
                              void* d_out, int out_size, void* d_ws, size_t ws_size,
                              hipStream_t stream) {
  const float* x      = (const float*)d_in[0];
  const float* w1     = (const float*)d_in[1];
  const float* b1     = (const float*)d_in[2];
  const float* gamma1 = (const float*)d_in[3];
  const float* beta1  = (const float*)d_in[4];
  const float* w2     = (const float*)d_in[5];
  const float* b2     = (const float*)d_in[6];
  const float* gamma2 = (const float*)d_in[7];
  const float* beta2  = (const float*)d_in[8];
  const float* gw1    = (const float*)d_in[9];
  const float* gb1    = (const float*)d_in[10];
  const float* gw2    = (const float*)d_in[11];
  const float* gb2    = (const float*)d_in[12];
  const float* gw3    = (const float*)d_in[13];
  const float* gb3    = (const float*)d_in[14];
  const float* ew1    = (const float*)d_in[15];
  const float* eb1    = (const float*)d_in[16];
  const float* ew2    = (const float*)d_in[17];
  const float* eb2    = (const float*)d_in[18];
  const float* ew3    = (const float*)d_in[19];
  const float* eb3    = (const float*)d_in[20];

  float* ws    = (float*)d_ws;
  float* h1raw = ws;
  float* h2raw = ws + 65536;
  float* bcp   = ws + 98304;
  float* stats = ws + 106496;
  unsigned short* aH = (unsigned short*)(ws + 106752);
  unsigned short* aL = (unsigned short*)(ws + 237824);
  float* p     = ws + 368896;   // 8 MB partials (also p3)
  float* outp  = (float*)d_out;

  hipMemsetAsync(stats, 0, 192 * sizeof(float), stream);
  enc_pre<<<256, 256, 0, stream>>>(x, w1, b1, h1raw, stats);
  enc_mid<<<256, 256, 0, stream>>>(h1raw, stats, gamma1, beta1, w2, b2, h2raw, stats + 128);
  gate_kernel<<<256, 256, 0, stream>>>(h2raw, stats + 128, gamma2, beta2,
                                       gw1, gb1, gw2, gb2, gw3, gb3, bcp);
  gen1<<<dim3(8, 2, 8), 256, 0, stream>>>(x, ew1, p);
  combine12<<<256, 256, 0, stream>>>(p, bcp, eb1, aH, aL);
  gen2<<<dim3(8, 2, 8), 256, 0, stream>>>(aH, aL, ew2, p);
  combine12<<<256, 256, 0, stream>>>(p, bcp, eb2, aH, aL);
  gen3<<<dim3(8, 1, 8), 256, 0, stream>>>(aH, aL, ew3, p);
  combine3<<<256, 256, 0, stream>>>(p, bcp, eb3, outp);
}